// Round 1
// baseline (374.745 us; speedup 1.0000x reference)
//
#include <hip/hip_runtime.h>
#include <hip/hip_bf16.h>
#include <cstdint>
#include <cstddef>

// Problem dims (fixed by the reference)
#define M_DIM 16384
#define IN_F  1024
#define OUT_F 2048
#define K_CAT 2048   // concatenated K = 2*IN_F

typedef float f32x4 __attribute__((ext_vector_type(4)));
typedef short short8 __attribute__((ext_vector_type(8)));   // 8 bf16 in 4 VGPRs

// ---------------------------------------------------------------------------
// async global->LDS, 16B per lane (global_load_lds_dwordx4)
// ---------------------------------------------------------------------------
__device__ __forceinline__ void gld_lds16(const void* gptr, void* lptr) {
    __builtin_amdgcn_global_load_lds(
        (const __attribute__((address_space(1))) uint32_t*)gptr,
        (__attribute__((address_space(3))) uint32_t*)lptr,
        16 /*bytes*/, 0 /*offset*/, 0 /*aux*/);
}

// ---------------------------------------------------------------------------
// prep_z: A = [bf16(z*z) | bf16(z)] as (M, 2048) row-major
// one thread = 4 consecutive floats of one row
// ---------------------------------------------------------------------------
__global__ __launch_bounds__(256) void prep_z_kernel(const float* __restrict__ z,
                                                     __hip_bfloat16* __restrict__ A) {
    const int idx = blockIdx.x * 256 + threadIdx.x;   // 0 .. M*IN_F/4-1
    const float4 v = ((const float4*)z)[idx];
    const int m  = idx >> 8;          // / (IN_F/4)
    const int c4 = (idx & 255) * 4;   // column within row
    __hip_bfloat16 q[4], r[4];
    q[0] = __float2bfloat16(v.x * v.x); r[0] = __float2bfloat16(v.x);
    q[1] = __float2bfloat16(v.y * v.y); r[1] = __float2bfloat16(v.y);
    q[2] = __float2bfloat16(v.z * v.z); r[2] = __float2bfloat16(v.z);
    q[3] = __float2bfloat16(v.w * v.w); r[3] = __float2bfloat16(v.w);
    __hip_bfloat16* rowp = A + (size_t)m * K_CAT;
    *(uint2*)&rowp[c4]        = *(uint2*)q;   // z^2 half
    *(uint2*)&rowp[IN_F + c4] = *(uint2*)r;   // z half
}

// ---------------------------------------------------------------------------
// prep_b: B[k,:] = [bf16(-d) | bf16(2*d*mean)] as (OUT_F, 2048) row-major (B^T)
//         mcm[k] = sum_i d*mean^2 ; ts[k] = tanh(scale[k])
// one block per k
// ---------------------------------------------------------------------------
__global__ __launch_bounds__(256) void prep_b_kernel(const float* __restrict__ diag,
                                                     const float* __restrict__ mean,
                                                     const float* __restrict__ scale,
                                                     __hip_bfloat16* __restrict__ B,
                                                     float* __restrict__ mcm,
                                                     float* __restrict__ ts) {
    const int k = blockIdx.x;
    const int t = threadIdx.x;
    const float4 dp = ((const float4*)(diag + (size_t)k * IN_F))[t];
    const float4 mp = ((const float4*)(mean + (size_t)k * IN_F))[t];
    const float dx[4] = {dp.x, dp.y, dp.z, dp.w};
    const float mx[4] = {mp.x, mp.y, mp.z, mp.w};
    __hip_bfloat16 nb[4], pb[4];
    float acc = 0.f;
#pragma unroll
    for (int j = 0; j < 4; ++j) {
        const float d = 0.1f + 0.9f / (1.f + __expf(-dx[j]));  // sigmoid clamp
        nb[j] = __float2bfloat16(-d);
        pb[j] = __float2bfloat16(2.f * d * mx[j]);
        acc += d * mx[j] * mx[j];
    }
    __hip_bfloat16* rowp = B + (size_t)k * K_CAT;
    *(uint2*)&rowp[t * 4]        = *(uint2*)nb;
    *(uint2*)&rowp[IN_F + t * 4] = *(uint2*)pb;
    // reduce acc over 256 threads (4 waves)
#pragma unroll
    for (int off = 32; off > 0; off >>= 1) acc += __shfl_down(acc, off);
    __shared__ float red[4];
    if ((t & 63) == 0) red[t >> 6] = acc;
    __syncthreads();
    if (t == 0) {
        mcm[k] = red[0] + red[1] + red[2] + red[3];
        ts[k]  = tanhf(scale[k]);
    }
}

// ---------------------------------------------------------------------------
// gemm_exp: out[m,k] = ts[k] * exp( A(m,:)·B(k,:) - mcm[k] )
// 128x128 tile, BK=64, 4 waves (2x2), 64x64 per wave, mfma 16x16x32 bf16
// ---------------------------------------------------------------------------
__global__ __launch_bounds__(256) void gemm_exp_kernel(
    const __hip_bfloat16* __restrict__ A,   // M x 2048
    const __hip_bfloat16* __restrict__ B,   // OUT_F x 2048
    const float* __restrict__ mcm,
    const float* __restrict__ ts,
    float* __restrict__ out) {
    __shared__ __align__(16) __hip_bfloat16 As[128][64];
    __shared__ __align__(16) __hip_bfloat16 Bs[128][64];

    const int t  = threadIdx.x;
    const int bx = blockIdx.x;
    const int tn = bx & 15;   // 16 N tiles  (consecutive blocks share A panel)
    const int tm = bx >> 4;   // 128 M tiles

    const int lrow  = t >> 3;        // 0..31 : LDS row within a 32-row stripe
    const int lcol8 = (t & 7) * 8;   // 16B chunk within 128B row
    const int wid  = t >> 6;
    const int lane = t & 63;
    const int wm = (wid >> 1) * 64;  // wave's M offset in tile
    const int wn = (wid & 1) * 64;   // wave's N offset in tile
    const int l15 = lane & 15;
    const int l4  = lane >> 4;

    f32x4 acc[4][4] = {};

    const __hip_bfloat16* aptr = A + (size_t)(tm * 128 + lrow) * K_CAT + lcol8;
    const __hip_bfloat16* bptr = B + (size_t)(tn * 128 + lrow) * K_CAT + lcol8;

    for (int kt = 0; kt < K_CAT / 64; ++kt) {
#pragma unroll
        for (int j = 0; j < 4; ++j) {
            gld_lds16(aptr + (size_t)j * 32 * K_CAT, &As[j * 32 + lrow][lcol8]);
            gld_lds16(bptr + (size_t)j * 32 * K_CAT, &Bs[j * 32 + lrow][lcol8]);
        }
        aptr += 64;
        bptr += 64;
        __syncthreads();   // compiler drains vmcnt before barrier

        short8 af[4][2], bfr[4][2];
#pragma unroll
        for (int fm = 0; fm < 4; ++fm)
#pragma unroll
            for (int kk = 0; kk < 2; ++kk)
                af[fm][kk] = *(const short8*)&As[wm + fm * 16 + l15][kk * 32 + l4 * 8];
#pragma unroll
        for (int fn = 0; fn < 4; ++fn)
#pragma unroll
            for (int kk = 0; kk < 2; ++kk)
                bfr[fn][kk] = *(const short8*)&Bs[wn + fn * 16 + l15][kk * 32 + l4 * 8];
#pragma unroll
        for (int kk = 0; kk < 2; ++kk)
#pragma unroll
            for (int fm = 0; fm < 4; ++fm)
#pragma unroll
                for (int fn = 0; fn < 4; ++fn)
                    acc[fm][fn] = __builtin_amdgcn_mfma_f32_16x16x32_bf16(
                        af[fm][kk], bfr[fn][kk], acc[fm][fn], 0, 0, 0);
        __syncthreads();
    }

    // epilogue: C/D layout col = lane&15, row = (lane>>4)*4 + reg  [m89-verified]
#pragma unroll
    for (int fn = 0; fn < 4; ++fn) {
        const int ng = tn * 128 + wn + fn * 16 + l15;
        const float tsv = ts[ng];
        const float mv  = mcm[ng];
#pragma unroll
        for (int fm = 0; fm < 4; ++fm) {
            const int mg0 = tm * 128 + wm + fm * 16 + l4 * 4;
#pragma unroll
            for (int r = 0; r < 4; ++r) {
                out[(size_t)(mg0 + r) * OUT_F + ng] = tsv * __expf(acc[fm][fn][r] - mv);
            }
        }
    }
}

// ---------------------------------------------------------------------------
extern "C" void kernel_launch(void* const* d_in, const int* in_sizes, int n_in,
                              void* d_out, int out_size, void* d_ws, size_t ws_size,
                              hipStream_t stream) {
    const float* z     = (const float*)d_in[0];   // (16384,1024)
    const float* diag  = (const float*)d_in[1];   // (2048,1024)
    const float* mean  = (const float*)d_in[2];   // (2048,1024,1)
    const float* scale = (const float*)d_in[3];   // (2048,)
    float* out = (float*)d_out;                   // (16384,2048)

    char* ws = (char*)d_ws;
    const size_t A_BYTES = (size_t)M_DIM * K_CAT * sizeof(__hip_bfloat16);  // 67.1 MB
    const size_t B_BYTES = (size_t)OUT_F * K_CAT * sizeof(__hip_bfloat16);  //  8.4 MB
    __hip_bfloat16* Abuf = (__hip_bfloat16*)ws;
    __hip_bfloat16* Bbuf = (__hip_bfloat16*)(ws + A_BYTES);
    float* mcm = (float*)(ws + A_BYTES + B_BYTES);
    float* ts  = (float*)(ws + A_BYTES + B_BYTES + 8192);

    prep_z_kernel<<<(M_DIM * IN_F / 4) / 256, 256, 0, stream>>>(z, Abuf);
    prep_b_kernel<<<OUT_F, 256, 0, stream>>>(diag, mean, scale, Bbuf, mcm, ts);
    gemm_exp_kernel<<<(M_DIM / 128) * (OUT_F / 128), 256, 0, stream>>>(
        Abuf, Bbuf, mcm, ts, out);
}

// Round 2
// 324.154 us; speedup vs baseline: 1.1561x; 1.1561x over previous
//
#include <hip/hip_runtime.h>
#include <hip/hip_bf16.h>
#include <cstdint>
#include <cstddef>

// Problem dims (fixed by the reference)
#define M_DIM 16384
#define IN_F  1024
#define OUT_F 2048
#define K_CAT 2048            // concatenated K = 2*IN_F
#define NT    (K_CAT / 32)    // 64 K-tiles of BK=32

typedef float f32x4 __attribute__((ext_vector_type(4)));
typedef short short8 __attribute__((ext_vector_type(8)));   // 8 bf16 in 4 VGPRs

// async global->LDS, 16B per lane (global_load_lds_dwordx4)
__device__ __forceinline__ void gld_lds16(const void* gptr, void* lptr) {
    __builtin_amdgcn_global_load_lds(
        (const __attribute__((address_space(1))) uint32_t*)gptr,
        (__attribute__((address_space(3))) uint32_t*)lptr,
        16 /*bytes*/, 0 /*offset*/, 0 /*aux*/);
}

// ---------------------------------------------------------------------------
// prep_z: A = [bf16(z*z) | bf16(z)] as (M, 2048) row-major. 8 floats/thread.
// ---------------------------------------------------------------------------
__global__ __launch_bounds__(256) void prep_z_kernel(const float* __restrict__ z,
                                                     __hip_bfloat16* __restrict__ A) {
    const int idx = blockIdx.x * 256 + threadIdx.x;   // 0 .. M*IN_F/8-1
    const int m  = idx >> 7;          // / (IN_F/8)
    const int c8 = (idx & 127) * 8;
    const float4 v0 = ((const float4*)z)[idx * 2];
    const float4 v1 = ((const float4*)z)[idx * 2 + 1];
    const float x[8] = {v0.x, v0.y, v0.z, v0.w, v1.x, v1.y, v1.z, v1.w};
    __hip_bfloat16 q[8], r[8];
#pragma unroll
    for (int j = 0; j < 8; ++j) {
        q[j] = __float2bfloat16(x[j] * x[j]);
        r[j] = __float2bfloat16(x[j]);
    }
    __hip_bfloat16* rowp = A + (size_t)m * K_CAT;
    *(uint4*)&rowp[c8]        = *(uint4*)q;   // z^2 half
    *(uint4*)&rowp[IN_F + c8] = *(uint4*)r;   // z half
}

// ---------------------------------------------------------------------------
// prep_b: B[k,:] = [bf16(-d) | bf16(2*d*mean)]  (OUT_F x 2048, B^T layout)
//         mcm[k] = sum_i d*mean^2 ; ts[k] = tanh(scale[k])
// ---------------------------------------------------------------------------
__global__ __launch_bounds__(256) void prep_b_kernel(const float* __restrict__ diag,
                                                     const float* __restrict__ mean,
                                                     const float* __restrict__ scale,
                                                     __hip_bfloat16* __restrict__ B,
                                                     float* __restrict__ mcm,
                                                     float* __restrict__ ts) {
    const int k = blockIdx.x;
    const int t = threadIdx.x;
    const float4 dp = ((const float4*)(diag + (size_t)k * IN_F))[t];
    const float4 mp = ((const float4*)(mean + (size_t)k * IN_F))[t];
    const float dx[4] = {dp.x, dp.y, dp.z, dp.w};
    const float mx[4] = {mp.x, mp.y, mp.z, mp.w};
    __hip_bfloat16 nb[4], pb[4];
    float acc = 0.f;
#pragma unroll
    for (int j = 0; j < 4; ++j) {
        const float d = 0.1f + 0.9f / (1.f + __expf(-dx[j]));  // sigmoid clamp
        nb[j] = __float2bfloat16(-d);
        pb[j] = __float2bfloat16(2.f * d * mx[j]);
        acc += d * mx[j] * mx[j];
    }
    __hip_bfloat16* rowp = B + (size_t)k * K_CAT;
    *(uint2*)&rowp[t * 4]        = *(uint2*)nb;
    *(uint2*)&rowp[IN_F + t * 4] = *(uint2*)pb;
#pragma unroll
    for (int off = 32; off > 0; off >>= 1) acc += __shfl_down(acc, off);
    __shared__ float red[4];
    if ((t & 63) == 0) red[t >> 6] = acc;
    __syncthreads();
    if (t == 0) {
        mcm[k] = red[0] + red[1] + red[2] + red[3];
        ts[k]  = tanhf(scale[k]);
    }
}

// ---------------------------------------------------------------------------
// gemm_exp: out[m,n] = ts[n] * exp( A(m,:)·B(n,:) - mcm[n] )
// BM=BN=256, BK=32, 8 waves (2M x 4N), per-wave 128x64.
// 4-deep LDS ring, counted vmcnt(8), raw s_barrier, setprio around MFMA.
// LDS tile [256][32] bf16: 64B rows -> frag ds_read_b128 is bank-conflict-free
// (16 rows x 4 k-subs tile all 32 banks exactly 8x = minimum).
// ---------------------------------------------------------------------------
__global__ __launch_bounds__(512, 2) void gemm_exp_kernel(
    const __hip_bfloat16* __restrict__ A,   // M x 2048
    const __hip_bfloat16* __restrict__ B,   // OUT_F x 2048 (B^T)
    const float* __restrict__ mcm,
    const float* __restrict__ ts,
    float* __restrict__ out) {
    __shared__ __align__(16) __hip_bfloat16 smem[4][2][8192];  // 4 bufs x (A,B) x 16KB

    const int t = threadIdx.x;
    // XCD-aware swizzle: nwg=512, 512%8==0 -> simple form is bijective.
    const int wg = ((blockIdx.x & 7) << 6) | (blockIdx.x >> 3);
    const int tn = wg & 7;    // 8 N tiles (consecutive wg share the A panel)
    const int tm = wg >> 3;   // 64 M tiles

    // --- staging addresses: chunk c covers LDS bytes [c*16, c*16+16) ---
    const int c0 = t, c1 = t + 512;
    const int r0 = c0 >> 2, s0 = c0 & 3;   // row in tile, 16B sub-chunk of 64B row
    const int r1 = c1 >> 2, s1 = c1 & 3;
    const __hip_bfloat16* gA0 = A + (size_t)(tm * 256 + r0) * K_CAT + s0 * 8;
    const __hip_bfloat16* gA1 = A + (size_t)(tm * 256 + r1) * K_CAT + s1 * 8;
    const __hip_bfloat16* gB0 = B + (size_t)(tn * 256 + r0) * K_CAT + s0 * 8;
    const __hip_bfloat16* gB1 = B + (size_t)(tn * 256 + r1) * K_CAT + s1 * 8;

#define ISSUE_A(buf_, kt_) do { \
        gld_lds16(gA0 + (kt_) * 32, &smem[buf_][0][c0 * 8]); \
        gld_lds16(gA1 + (kt_) * 32, &smem[buf_][0][c1 * 8]); } while (0)
#define ISSUE_B(buf_, kt_) do { \
        gld_lds16(gB0 + (kt_) * 32, &smem[buf_][1][c0 * 8]); \
        gld_lds16(gB1 + (kt_) * 32, &smem[buf_][1][c1 * 8]); } while (0)

    // --- fragment read offsets (bf16 elements) ---
    const int wid = t >> 6, lane = t & 63;
    const int wmb = (wid >> 2) * 128;   // wave M base within tile
    const int wnb = (wid & 3) * 64;     // wave N base within tile
    const int l15 = lane & 15, l4 = lane >> 4;
    int offA[8], offB[4];
#pragma unroll
    for (int fm = 0; fm < 8; ++fm) offA[fm] = (wmb + fm * 16 + l15) * 32 + l4 * 8;
#pragma unroll
    for (int fn = 0; fn < 4; ++fn) offB[fn] = (wnb + fn * 16 + l15) * 32 + l4 * 8;

    f32x4 acc[8][4] = {};

    // --- prologue: stage tiles 0,1,2 into bufs 0,1,2 (12 loads/thread) ---
    ISSUE_A(0, 0); ISSUE_B(0, 0);
    ISSUE_A(1, 1); ISSUE_B(1, 1);
    ISSUE_A(2, 2); ISSUE_B(2, 2);
    asm volatile("s_waitcnt vmcnt(8)" ::: "memory");   // tile 0 landed
    __builtin_amdgcn_s_barrier();
    __builtin_amdgcn_sched_barrier(0);

    // --- main loop: 64 K-tiles, 2 phases each ---
#pragma unroll 4
    for (int kt = 0; kt < NT; ++kt) {
        const int buf  = kt & 3;
        const int pf   = (kt < NT - 3) ? kt + 3 : NT - 1;  // clamped dummy prefetch
        const int pbuf = (kt + 3) & 3;                     // provably-dead buffer

        // ---- phase 1: read B(all) + A(m0-3); issue A prefetch ----
        short8 bfr[4], af0[4];
#pragma unroll
        for (int fn = 0; fn < 4; ++fn) bfr[fn] = *(const short8*)&smem[buf][1][offB[fn]];
#pragma unroll
        for (int fm = 0; fm < 4; ++fm) af0[fm] = *(const short8*)&smem[buf][0][offA[fm]];
        ISSUE_A(pbuf, pf);
        __builtin_amdgcn_sched_barrier(0);
        __builtin_amdgcn_s_barrier();
        asm volatile("s_waitcnt lgkmcnt(0)" ::: "memory");
        __builtin_amdgcn_sched_barrier(0);
        __builtin_amdgcn_s_setprio(1);
#pragma unroll
        for (int fm = 0; fm < 4; ++fm)
#pragma unroll
            for (int fn = 0; fn < 4; ++fn)
                acc[fm][fn] = __builtin_amdgcn_mfma_f32_16x16x32_bf16(
                    af0[fm], bfr[fn], acc[fm][fn], 0, 0, 0);
        __builtin_amdgcn_s_setprio(0);
        __builtin_amdgcn_sched_barrier(0);
        __builtin_amdgcn_s_barrier();

        // ---- phase 2: read A(m4-7); issue B prefetch; counted vmcnt ----
        short8 af1[4];
#pragma unroll
        for (int fm = 0; fm < 4; ++fm) af1[fm] = *(const short8*)&smem[buf][0][offA[fm + 4]];
        ISSUE_B(pbuf, pf);
        __builtin_amdgcn_sched_barrier(0);
        __builtin_amdgcn_s_barrier();
        asm volatile("s_waitcnt lgkmcnt(0)" ::: "memory");
        __builtin_amdgcn_sched_barrier(0);
        __builtin_amdgcn_s_setprio(1);
#pragma unroll
        for (int fm = 0; fm < 4; ++fm)
#pragma unroll
            for (int fn = 0; fn < 4; ++fn)
                acc[fm + 4][fn] = __builtin_amdgcn_mfma_f32_16x16x32_bf16(
                    af1[fm], bfr[fn], acc[fm + 4][fn], 0, 0, 0);
        __builtin_amdgcn_s_setprio(0);
        __builtin_amdgcn_sched_barrier(0);
        // tile kt+1 must be fully landed before next iteration's ds_reads;
        // leaves tiles kt+2, kt+3 (8 loads) in flight -> never drains to 0.
        asm volatile("s_waitcnt vmcnt(8)" ::: "memory");
        __builtin_amdgcn_s_barrier();
        __builtin_amdgcn_sched_barrier(0);
    }
#undef ISSUE_A
#undef ISSUE_B

    // --- epilogue: C/D layout col=lane&15 (N), row=(lane>>4)*4+reg (M) ---
#pragma unroll
    for (int fn = 0; fn < 4; ++fn) {
        const int gn = tn * 256 + wnb + fn * 16 + l15;
        const float tsv = ts[gn];
        const float mv  = mcm[gn];
#pragma unroll
        for (int fm = 0; fm < 8; ++fm) {
            const int gm0 = tm * 256 + wmb + fm * 16 + l4 * 4;
#pragma unroll
            for (int r = 0; r < 4; ++r)
                out[(size_t)(gm0 + r) * OUT_F + gn] = tsv * __expf(acc[fm][fn][r] - mv);
        }
    }
}

// ---------------------------------------------------------------------------
extern "C" void kernel_launch(void* const* d_in, const int* in_sizes, int n_in,
                              void* d_out, int out_size, void* d_ws, size_t ws_size,
                              hipStream_t stream) {
    const float* z     = (const float*)d_in[0];   // (16384,1024)
    const float* diag  = (const float*)d_in[1];   // (2048,1024)
    const float* mean  = (const float*)d_in[2];   // (2048,1024,1)
    const float* scale = (const float*)d_in[3];   // (2048,)
    float* out = (float*)d_out;                   // (16384,2048)

    char* ws = (char*)d_ws;
    const size_t A_BYTES = (size_t)M_DIM * K_CAT * sizeof(__hip_bfloat16);  // 67.1 MB
    const size_t B_BYTES = (size_t)OUT_F * K_CAT * sizeof(__hip_bfloat16);  //  8.4 MB
    __hip_bfloat16* Abuf = (__hip_bfloat16*)ws;
    __hip_bfloat16* Bbuf = (__hip_bfloat16*)(ws + A_BYTES);
    float* mcm = (float*)(ws + A_BYTES + B_BYTES);
    float* ts  = (float*)(ws + A_BYTES + B_BYTES + 8192);

    prep_z_kernel<<<(M_DIM * IN_F / 8) / 256, 256, 0, stream>>>(z, Abuf);
    prep_b_kernel<<<OUT_F, 256, 0, stream>>>(diag, mean, scale, Bbuf, mcm, ts);
    gemm_exp_kernel<<<(M_DIM / 256) * (OUT_F / 256), 512, 0, stream>>>(
        Abuf, Bbuf, mcm, ts, out);
}

// Round 4
// 315.689 us; speedup vs baseline: 1.1871x; 1.0268x over previous
//
#include <hip/hip_runtime.h>
#include <hip/hip_bf16.h>
#include <cstdint>
#include <cstddef>

// Problem dims (fixed by the reference)
#define M_DIM 16384
#define IN_F  1024
#define OUT_F 2048
#define K_CAT 2048            // concatenated K = 2*IN_F
#define NT    (K_CAT / 32)    // 64 K-tiles of BK=32

typedef float f32x4 __attribute__((ext_vector_type(4)));
typedef short short8 __attribute__((ext_vector_type(8)));   // 8 bf16 in 4 VGPRs

// async global->LDS, 16B per lane (global_load_lds_dwordx4)
__device__ __forceinline__ void gld_lds16(const void* gptr, void* lptr) {
    __builtin_amdgcn_global_load_lds(
        (const __attribute__((address_space(1))) uint32_t*)gptr,
        (__attribute__((address_space(3))) uint32_t*)lptr,
        16 /*bytes*/, 0 /*offset*/, 0 /*aux*/);
}

// ---------------------------------------------------------------------------
// prep_z: A = [bf16(z*z) | bf16(z)] as (M, 2048) row-major. 8 floats/thread.
// ---------------------------------------------------------------------------
__global__ __launch_bounds__(256) void prep_z_kernel(const float* __restrict__ z,
                                                     __hip_bfloat16* __restrict__ A) {
    const int idx = blockIdx.x * 256 + threadIdx.x;   // 0 .. M*IN_F/8-1
    const int m  = idx >> 7;          // / (IN_F/8)
    const int c8 = (idx & 127) * 8;
    const float4 v0 = ((const float4*)z)[idx * 2];
    const float4 v1 = ((const float4*)z)[idx * 2 + 1];
    const float x[8] = {v0.x, v0.y, v0.z, v0.w, v1.x, v1.y, v1.z, v1.w};
    __hip_bfloat16 q[8], r[8];
#pragma unroll
    for (int j = 0; j < 8; ++j) {
        q[j] = __float2bfloat16(x[j] * x[j]);
        r[j] = __float2bfloat16(x[j]);
    }
    __hip_bfloat16* rowp = A + (size_t)m * K_CAT;
    *(uint4*)&rowp[c8]        = *(uint4*)q;   // z^2 half
    *(uint4*)&rowp[IN_F + c8] = *(uint4*)r;   // z half
}

// ---------------------------------------------------------------------------
// prep_b: B[k,:] = [bf16(-d) | bf16(2*d*mean)]  (OUT_F x 2048, B^T layout)
//         mcm[k] = sum_i d*mean^2 ; ts[k] = tanh(scale[k])
// ---------------------------------------------------------------------------
__global__ __launch_bounds__(256) void prep_b_kernel(const float* __restrict__ diag,
                                                     const float* __restrict__ mean,
                                                     const float* __restrict__ scale,
                                                     __hip_bfloat16* __restrict__ B,
                                                     float* __restrict__ mcm,
                                                     float* __restrict__ ts) {
    const int k = blockIdx.x;
    const int t = threadIdx.x;
    const float4 dp = ((const float4*)(diag + (size_t)k * IN_F))[t];
    const float4 mp = ((const float4*)(mean + (size_t)k * IN_F))[t];
    const float dx[4] = {dp.x, dp.y, dp.z, dp.w};
    const float mx[4] = {mp.x, mp.y, mp.z, mp.w};
    __hip_bfloat16 nb[4], pb[4];
    float acc = 0.f;
#pragma unroll
    for (int j = 0; j < 4; ++j) {
        const float d = 0.1f + 0.9f / (1.f + __expf(-dx[j]));  // sigmoid clamp
        nb[j] = __float2bfloat16(-d);
        pb[j] = __float2bfloat16(2.f * d * mx[j]);
        acc += d * mx[j] * mx[j];
    }
    __hip_bfloat16* rowp = B + (size_t)k * K_CAT;
    *(uint2*)&rowp[t * 4]        = *(uint2*)nb;
    *(uint2*)&rowp[IN_F + t * 4] = *(uint2*)pb;
#pragma unroll
    for (int off = 32; off > 0; off >>= 1) acc += __shfl_down(acc, off);
    __shared__ float red[4];
    if ((t & 63) == 0) red[t >> 6] = acc;
    __syncthreads();
    if (t == 0) {
        mcm[k] = red[0] + red[1] + red[2] + red[3];
        ts[k]  = tanhf(scale[k]);
    }
}

// ---------------------------------------------------------------------------
// gemm_exp: out[m,n] = ts[n] * exp( A(m,:)·B(n,:) - mcm[n] )
// BM=BN=256, BK=32, 8 waves (2M x 4N), per-wave 128x64.
// 4-deep LDS ring, counted vmcnt(8), ONE barrier per kt, setprio on MFMA.
// LDS bank-conflict fix: k-slot XOR swizzle (slot u at row r holds global
// k-sub u^((r>>1)&3)); applied on BOTH the staging global-source address
// (LDS dest stays linear for global_load_lds) and the ds_read offset.
// ---------------------------------------------------------------------------
__global__ __launch_bounds__(512, 2) void gemm_exp_kernel(
    const __hip_bfloat16* __restrict__ A,   // M x 2048
    const __hip_bfloat16* __restrict__ B,   // OUT_F x 2048 (B^T)
    const float* __restrict__ mcm,
    const float* __restrict__ ts,
    float* __restrict__ out) {
    __shared__ __align__(16) __hip_bfloat16 smem[4][2][8192];  // 4 bufs x (A,B) x 16KB

    const int t = threadIdx.x;
    // XCD-aware swizzle: nwg=512, 512%8==0 -> simple form is bijective.
    const int wg = ((blockIdx.x & 7) << 6) | (blockIdx.x >> 3);
    const int tn = wg & 7;    // 8 N tiles (consecutive wg share the A panel)
    const int tm = wg >> 3;   // 64 M tiles

    // --- staging: chunk c covers LDS bytes [c*16, c*16+16) ---
    // row = c>>2 (64B rows), LDS 16B-slot u = c&3 holds global k-sub u^((row>>1)&3)
    const int c0 = t, c1 = t + 512;
    const int r0 = c0 >> 2, u0 = c0 & 3;
    const int r1 = c1 >> 2, u1 = c1 & 3;
    const int s0 = u0 ^ ((r0 >> 1) & 3);
    const int s1 = u1 ^ ((r1 >> 1) & 3);
    const __hip_bfloat16* gA0 = A + (size_t)(tm * 256 + r0) * K_CAT + s0 * 8;
    const __hip_bfloat16* gA1 = A + (size_t)(tm * 256 + r1) * K_CAT + s1 * 8;
    const __hip_bfloat16* gB0 = B + (size_t)(tn * 256 + r0) * K_CAT + s0 * 8;
    const __hip_bfloat16* gB1 = B + (size_t)(tn * 256 + r1) * K_CAT + s1 * 8;

#define ISSUE_A(buf_, kt_) do { \
        gld_lds16(gA0 + (kt_) * 32, &smem[buf_][0][c0 * 8]); \
        gld_lds16(gA1 + (kt_) * 32, &smem[buf_][0][c1 * 8]); } while (0)
#define ISSUE_B(buf_, kt_) do { \
        gld_lds16(gB0 + (kt_) * 32, &smem[buf_][1][c0 * 8]); \
        gld_lds16(gB1 + (kt_) * 32, &smem[buf_][1][c1 * 8]); } while (0)

    // --- fragment read offsets (bf16 elements), swizzled k-slot ---
    const int wid = t >> 6, lane = t & 63;
    const int wmb = (wid >> 2) * 128;   // wave M base within tile
    const int wnb = (wid & 3) * 64;     // wave N base within tile
    const int l15 = lane & 15, l4 = lane >> 4;
    int offA[8], offB[4];
#pragma unroll
    for (int fm = 0; fm < 8; ++fm) {
        const int r = wmb + fm * 16 + l15;
        offA[fm] = r * 32 + (l4 ^ ((r >> 1) & 3)) * 8;
    }
#pragma unroll
    for (int fn = 0; fn < 4; ++fn) {
        const int r = wnb + fn * 16 + l15;
        offB[fn] = r * 32 + (l4 ^ ((r >> 1) & 3)) * 8;
    }

    f32x4 acc[8][4] = {};

    // --- prologue: stage tiles 0,1,2 into bufs 0,1,2 (12 loads/thread) ---
    ISSUE_A(0, 0); ISSUE_B(0, 0);
    ISSUE_A(1, 1); ISSUE_B(1, 1);
    ISSUE_A(2, 2); ISSUE_B(2, 2);
    asm volatile("s_waitcnt vmcnt(8)" ::: "memory");   // tile 0 landed
    __builtin_amdgcn_s_barrier();
    __builtin_amdgcn_sched_barrier(0);

    // --- main loop: 64 K-tiles, single phase, one barrier per kt ---
#pragma unroll 4
    for (int kt = 0; kt < NT; ++kt) {
        const int buf  = kt & 3;
        const int pf   = (kt < NT - 3) ? kt + 3 : NT - 1;  // clamped dummy prefetch
        const int pbuf = (kt + 3) & 3;                     // provably-dead buffer

        short8 bfr[4], af[8];
#pragma unroll
        for (int fn = 0; fn < 4; ++fn) bfr[fn] = *(const short8*)&smem[buf][1][offB[fn]];
#pragma unroll
        for (int fm = 0; fm < 8; ++fm) af[fm]  = *(const short8*)&smem[buf][0][offA[fm]];
        ISSUE_A(pbuf, pf);
        ISSUE_B(pbuf, pf);
        __builtin_amdgcn_sched_barrier(0);
        asm volatile("s_waitcnt lgkmcnt(0)" ::: "memory");  // own ds_reads done
        __builtin_amdgcn_sched_barrier(0);
        __builtin_amdgcn_s_setprio(1);
#pragma unroll
        for (int fm = 0; fm < 8; ++fm)
#pragma unroll
            for (int fn = 0; fn < 4; ++fn)
                acc[fm][fn] = __builtin_amdgcn_mfma_f32_16x16x32_bf16(
                    af[fm], bfr[fn], acc[fm][fn], 0, 0, 0);
        __builtin_amdgcn_s_setprio(0);
        __builtin_amdgcn_sched_barrier(0);
        // tile kt+1 fully landed; leaves 8 loads (tiles kt+2,kt+3) in flight.
        asm volatile("s_waitcnt vmcnt(8)" ::: "memory");
        __builtin_amdgcn_s_barrier();
        __builtin_amdgcn_sched_barrier(0);
    }
#undef ISSUE_A
#undef ISSUE_B

    // --- epilogue: C/D layout col=lane&15 (N), row=(lane>>4)*4+reg (M) ---
#pragma unroll
    for (int fn = 0; fn < 4; ++fn) {
        const int gn = tn * 256 + wnb + fn * 16 + l15;
        const float tsv = ts[gn];
        const float mv  = mcm[gn];
#pragma unroll
        for (int fm = 0; fm < 8; ++fm) {
            const int gm0 = tm * 256 + wmb + fm * 16 + l4 * 4;
#pragma unroll
            for (int r = 0; r < 4; ++r)
                out[(size_t)(gm0 + r) * OUT_F + gn] = tsv * __expf(acc[fm][fn][r] - mv);
        }
    }
}

// ---------------------------------------------------------------------------
extern "C" void kernel_launch(void* const* d_in, const int* in_sizes, int n_in,
                              void* d_out, int out_size, void* d_ws, size_t ws_size,
                              hipStream_t stream) {
    const float* z     = (const float*)d_in[0];   // (16384,1024)
    const float* diag  = (const float*)d_in[1];   // (2048,1024)
    const float* mean  = (const float*)d_in[2];   // (2048,1024,1)
    const float* scale = (const float*)d_in[3];   // (2048,)
    float* out = (float*)d_out;                   // (16384,2048)

    char* ws = (char*)d_ws;
    const size_t A_BYTES = (size_t)M_DIM * K_CAT * sizeof(__hip_bfloat16);  // 67.1 MB
    const size_t B_BYTES = (size_t)OUT_F * K_CAT * sizeof(__hip_bfloat16);  //  8.4 MB
    __hip_bfloat16* Abuf = (__hip_bfloat16*)ws;
    __hip_bfloat16* Bbuf = (__hip_bfloat16*)(ws + A_BYTES);
    float* mcm = (float*)(ws + A_BYTES + B_BYTES);
    float* ts  = (float*)(ws + A_BYTES + B_BYTES + 8192);

    prep_z_kernel<<<(M_DIM * IN_F / 8) / 256, 256, 0, stream>>>(z, Abuf);
    prep_b_kernel<<<OUT_F, 256, 0, stream>>>(diag, mean, scale, Bbuf, mcm, ts);
    gemm_exp_kernel<<<(M_DIM / 256) * (OUT_F / 256), 512, 0, stream>>>(
        Abuf, Bbuf, mcm, ts, out);
}